// Round 13
// baseline (318.606 us; speedup 1.0000x reference)
//
#include <hip/hip_runtime.h>
#include <hip/hip_bf16.h>

#define N_NODES 10000
#define M_PAD   10112   // 158*64
#define F_IN    128
#define H_DIM   512
#define N_CLS   7
#define NCHUNK  8
#define CCOLS   (H_DIM / NCHUNK)   // 64

typedef __bf16  bf16x8  __attribute__((ext_vector_type(8)));
typedef float   f32x4   __attribute__((ext_vector_type(4)));
typedef ushort  ushort8 __attribute__((ext_vector_type(8)));

__device__ __forceinline__ ushort f2bf(float f) {
    union { float f; unsigned u; } x; x.f = f;
    unsigned r = x.u + 0x7fffu + ((x.u >> 16) & 1u);
    return (ushort)(r >> 16);
}
__device__ __forceinline__ float bf2f(ushort h) {
    union { unsigned u; float f; } x; x.u = ((unsigned)h) << 16;
    return x.f;
}

__device__ __forceinline__ void gload16(const void* g, void* l) {
    __builtin_amdgcn_global_load_lds(
        (const __attribute__((address_space(1))) void*)g,
        (__attribute__((address_space(3))) void*)l, 16, 0, 0);
}

// ---------------- CSR build ----------------

__global__ void k_zero_i32(int* __restrict__ p, int n) {
    int i = blockIdx.x * blockDim.x + threadIdx.x;
    if (i < n) p[i] = 0;
}

__global__ void k_hist(const int* __restrict__ ei, int* __restrict__ counts, int E) {
    int e = blockIdx.x * blockDim.x + threadIdx.x;
    if (e < E) atomicAdd(&counts[ei[E + e]], 1);  // dst
}

__global__ __launch_bounds__(1024) void k_scan(const int* __restrict__ counts,
                                               int* __restrict__ offsets,
                                               int* __restrict__ cursor,
                                               int N, int E) {
    __shared__ int sm[1024];
    int t = threadIdx.x;
    int base = t * 10;
    int loc[10];
    int s = 0;
    #pragma unroll
    for (int i = 0; i < 10; ++i) {
        int idx = base + i;
        int c = (idx < N) ? counts[idx] : 0;
        loc[i] = s;
        s += c;
    }
    sm[t] = s;
    __syncthreads();
    for (int off = 1; off < 1024; off <<= 1) {
        int v = (t >= off) ? sm[t - off] : 0;
        __syncthreads();
        sm[t] += v;
        __syncthreads();
    }
    int excl = sm[t] - s;
    #pragma unroll
    for (int i = 0; i < 10; ++i) {
        int idx = base + i;
        if (idx < N) {
            int o = excl + loc[i];
            offsets[idx] = o;
            cursor[idx] = o;
        }
    }
    if (t == 0) offsets[N] = E;
}

__global__ void k_scatter(const int* __restrict__ ei, int* __restrict__ cursor,
                          int* __restrict__ csr_src, int E) {
    int e = blockIdx.x * blockDim.x + threadIdx.x;
    if (e < E) {
        int d = ei[E + e];
        int pos = atomicAdd(&cursor[d], 1);
        csr_src[pos] = ei[e];
    }
}

// ---------------- weight split, all 4 matrices in ONE launch ----------------
// W (K x N fp32) -> Wt_hi/Wt_lo (N x K bf16). LDS 32x33 tile transpose,
// coalesced read and write. blockIdx.z selects the matrix; z==0 (W1a) has
// K=128 so x-tiles beyond 4 early-return.

__global__ __launch_bounds__(256) void k_wsplit_all(
    const float* __restrict__ W0, ushort* __restrict__ T0h, ushort* __restrict__ T0l,
    const float* __restrict__ W1, ushort* __restrict__ T1h, ushort* __restrict__ T1l,
    const float* __restrict__ W2, ushort* __restrict__ T2h, ushort* __restrict__ T2l,
    const float* __restrict__ W3, ushort* __restrict__ T3h, ushort* __restrict__ T3l) {
    const int z = blockIdx.z;
    const int K = (z == 0) ? F_IN : H_DIM;
    const int N = H_DIM;
    if (blockIdx.x * 32 >= K) return;
    const float* W;
    ushort *Th, *Tl;
    if (z == 0)      { W = W0; Th = T0h; Tl = T0l; }
    else if (z == 1) { W = W1; Th = T1h; Tl = T1l; }
    else if (z == 2) { W = W2; Th = T2h; Tl = T2l; }
    else             { W = W3; Th = T3h; Tl = T3l; }

    __shared__ float tile[32][33];
    const int bk = blockIdx.x * 32;
    const int bn = blockIdx.y * 32;
    const int c  = threadIdx.x & 31;
    const int r0 = threadIdx.x >> 5;   // 0..7
    #pragma unroll
    for (int i = 0; i < 4; ++i) {
        const int r = r0 + i * 8;
        tile[r][c] = W[(size_t)(bk + r) * N + bn + c];
    }
    __syncthreads();
    #pragma unroll
    for (int i = 0; i < 4; ++i) {
        const int r = r0 + i * 8;          // n-offset
        const float w = tile[c][r];        // = W[bk+c][bn+r]
        const ushort hb = f2bf(w);
        const size_t o = (size_t)(bn + r) * K + bk + c;   // consecutive c -> coalesced
        Th[o] = hb;
        Tl[o] = f2bf(w - bf2f(hb));
    }
}

// ---------------- GIN agg, fp32 input (F=128): 2 nodes/wave, float4/lane ----------------
// 32 lanes per node x float4 halves the gather-instruction count vs
// 64-lane float2 (issue-bound kernel). Halves diverge on degree; cost is
// max(deg) not sum.

__global__ __launch_bounds__(256) void k_agg_f32(
    const float* __restrict__ X, const int* __restrict__ csr,
    const int* __restrict__ offs, const float* __restrict__ eps,
    ushort* __restrict__ Oh, ushort* __restrict__ Ol) {
    const int wv = threadIdx.x >> 6, lane = threadIdx.x & 63;
    const int half = lane >> 5, sub = lane & 31;
    const int n = blockIdx.x * 8 + wv * 2 + half;
    if (n >= N_NODES) return;
    const int c0 = sub * 4;
    const int s0 = offs[n], s1 = offs[n + 1];
    float4 a = {0.f, 0.f, 0.f, 0.f};
    for (int i = s0; i < s1; ++i) {
        const float4 v = *(const float4*)(X + (size_t)csr[i] * F_IN + c0);
        a.x += v.x; a.y += v.y; a.z += v.z; a.w += v.w;
    }
    const float4 sv = *(const float4*)(X + (size_t)n * F_IN + c0);
    const float e = 1.f + eps[0];
    const float v0 = e * sv.x + a.x;
    const float v1 = e * sv.y + a.y;
    const float v2 = e * sv.z + a.z;
    const float v3 = e * sv.w + a.w;
    ushort4 oh, ol;
    oh.x = f2bf(v0); ol.x = f2bf(v0 - bf2f(oh.x));
    oh.y = f2bf(v1); ol.y = f2bf(v1 - bf2f(oh.y));
    oh.z = f2bf(v2); ol.z = f2bf(v2 - bf2f(oh.z));
    oh.w = f2bf(v3); ol.w = f2bf(v3 - bf2f(oh.w));
    const size_t o = (size_t)n * F_IN + c0;
    *(ushort4*)(Oh + o) = oh;
    *(ushort4*)(Ol + o) = ol;
}

// ---------------- GIN agg, pair input (F=512): XCD column-chunked ----------------
// (VMEM-issue floor ~33us: 20.5M 16B gathers at ~1 load/cyc/CU.)

__global__ __launch_bounds__(256) void k_agg_pair(
    const ushort* __restrict__ Xh, const ushort* __restrict__ Xl,
    const int* __restrict__ csr, const int* __restrict__ offs,
    const float* __restrict__ eps,
    ushort* __restrict__ Oh, ushort* __restrict__ Ol) {
    const int chunk = blockIdx.x & (NCHUNK - 1);
    const int grp   = blockIdx.x >> 3;
    const int tid   = threadIdx.x;
    const int n     = grp * 16 + (tid >> 4);
    const int sub   = tid & 15;
    const int plane = sub >> 3;
    const int col   = chunk * CCOLS + (sub & 7) * 8;
    const ushort* __restrict__ X = plane ? Xl : Xh;

    const int s0 = offs[n], s1 = offs[n + 1];
    float acc[8] = {0.f, 0.f, 0.f, 0.f, 0.f, 0.f, 0.f, 0.f};
    for (int i = s0; i < s1; ++i) {
        const ushort8 v = *(const ushort8*)(X + (size_t)csr[i] * H_DIM + col);
        #pragma unroll
        for (int r = 0; r < 8; ++r) acc[r] += bf2f(v[r]);
    }
    {
        const ushort8 sv = *(const ushort8*)(X + (size_t)n * H_DIM + col);
        const float e = 1.f + eps[0];
        #pragma unroll
        for (int r = 0; r < 8; ++r) acc[r] += e * bf2f(sv[r]);
    }
    float tot[8];
    #pragma unroll
    for (int r = 0; r < 8; ++r) tot[r] = acc[r] + __shfl_xor(acc[r], 8, 64);
    if (plane == 0) {
        ushort8 oh, ol;
        #pragma unroll
        for (int r = 0; r < 8; ++r) {
            oh[r] = f2bf(tot[r]);
            ol[r] = f2bf(tot[r] - bf2f(oh[r]));
        }
        const size_t o = (size_t)n * H_DIM + col;
        *(ushort8*)(Oh + o) = oh;
        *(ushort8*)(Ol + o) = ol;
    }
}

// ---------------- split-bf16 MFMA GEMM (single-buffered — round-10 version) ----
// Explicit dbuf was neutral (m99/m100 pattern confirmed in round 12): implicit
// wave-level overlap at 6 blocks/CU already hides staging latency.

template <int DO_BN>
__global__ __launch_bounds__(256) void k_gemm_mfma(
    const ushort* __restrict__ Ah, const ushort* __restrict__ Al,
    const ushort* __restrict__ Wh, const ushort* __restrict__ Wlo,
    const float* __restrict__ bias,
    const float* __restrict__ g, const float* __restrict__ be,
    const float* __restrict__ rm, const float* __restrict__ rv,
    ushort* __restrict__ Oh, ushort* __restrict__ Ol,
    int K, int Nout) {
    __shared__ __align__(16) ushort As_h[64][32];
    __shared__ __align__(16) ushort As_l[64][32];
    __shared__ __align__(16) ushort Bs_h[128][32];
    __shared__ __align__(16) ushort Bs_l[128][32];

    const int tid  = threadIdx.x;
    const int lane = tid & 63;
    const int wid  = tid >> 6;
    const int wm   = wid >> 1, wn = wid & 1;   // 2x2 waves, wave tile 32x64
    const int bm = blockIdx.x * 64, bn = blockIdx.y * 128;
    const int rsel = lane & 15;
    const int kh   = (lane >> 4) * 8;

    f32x4 acc[2][4];
    #pragma unroll
    for (int m = 0; m < 2; ++m)
        #pragma unroll
        for (int n = 0; n < 4; ++n) {
            acc[m][n][0] = 0.f; acc[m][n][1] = 0.f;
            acc[m][n][2] = 0.f; acc[m][n][3] = 0.f;
        }

    for (int k0 = 0; k0 < K; k0 += 32) {
        {
            const int off = tid * 16;          // A: 64x32 = 4KB/plane
            const int row = off >> 6;
            const int ke  = (off & 63) >> 1;
            const size_t ga = (size_t)(bm + row) * K + (k0 + ke);
            gload16(Ah + ga, (char*)As_h + off);
            gload16(Al + ga, (char*)As_l + off);
        }
        #pragma unroll
        for (int c = 0; c < 2; ++c) {
            const int off = tid * 16 + c * 4096;  // B: 128x32 = 8KB/plane
            const int row = off >> 6;
            const int ke  = (off & 63) >> 1;
            const size_t gb = (size_t)(bn + row) * K + (k0 + ke);
            gload16(Wh + gb,  (char*)Bs_h + off);
            gload16(Wlo + gb, (char*)Bs_l + off);
        }
        __syncthreads();
        bf16x8 a_h[2], a_l[2], b_h[4], b_l[4];
        #pragma unroll
        for (int m = 0; m < 2; ++m) {
            const int r = wm * 32 + m * 16 + rsel;
            a_h[m] = *(const bf16x8*)&As_h[r][kh];
            a_l[m] = *(const bf16x8*)&As_l[r][kh];
        }
        #pragma unroll
        for (int n = 0; n < 4; ++n) {
            const int r = wn * 64 + n * 16 + rsel;
            b_h[n] = *(const bf16x8*)&Bs_h[r][kh];
            b_l[n] = *(const bf16x8*)&Bs_l[r][kh];
        }
        #pragma unroll
        for (int m = 0; m < 2; ++m)
            #pragma unroll
            for (int n = 0; n < 4; ++n) {
                acc[m][n] = __builtin_amdgcn_mfma_f32_16x16x32_bf16(a_h[m], b_h[n], acc[m][n], 0, 0, 0);
                acc[m][n] = __builtin_amdgcn_mfma_f32_16x16x32_bf16(a_h[m], b_l[n], acc[m][n], 0, 0, 0);
                acc[m][n] = __builtin_amdgcn_mfma_f32_16x16x32_bf16(a_l[m], b_h[n], acc[m][n], 0, 0, 0);
            }
        __syncthreads();
    }

    float bs[4], sc[4], sh[4];
    int cols[4];
    #pragma unroll
    for (int n = 0; n < 4; ++n) {
        const int col = bn + wn * 64 + n * 16 + rsel;
        cols[n] = col;
        bs[n] = bias[col];
        if (DO_BN) {
            const float s = g[col] * rsqrtf(rv[col] + 1e-5f);
            sc[n] = s;
            sh[n] = be[col] - rm[col] * s;
        } else {
            sc[n] = 0.f; sh[n] = 0.f;
        }
    }
    #pragma unroll
    for (int m = 0; m < 2; ++m) {
        #pragma unroll
        for (int r = 0; r < 4; ++r) {
            const int row = bm + wm * 32 + m * 16 + (lane >> 4) * 4 + r;
            #pragma unroll
            for (int n = 0; n < 4; ++n) {
                float v = acc[m][n][r] + bs[n];
                v = fmaxf(v, 0.f);
                if (DO_BN) v = v * sc[n] + sh[n];
                const ushort hb = f2bf(v);
                const ushort lb = f2bf(v - bf2f(hb));
                const size_t o = (size_t)row * Nout + cols[n];
                Oh[o] = hb;
                Ol[o] = lb;
            }
        }
    }
}

// ---------------- edge head: out[t] = (h[a]*h[b]) @ Wf + bf ----------------

__global__ __launch_bounds__(256) void k_edge(
    const ushort* __restrict__ hh, const ushort* __restrict__ hl,
    const int* __restrict__ ei, const int* __restrict__ tids,
    const float* __restrict__ Wf, const float* __restrict__ bf_,
    float* __restrict__ out, int Etr, int E) {
    const int lane = threadIdx.x & 63;
    const int wv   = threadIdx.x >> 6;
    float wfr[8][N_CLS];
    #pragma unroll
    for (int r = 0; r < 8; ++r)
        #pragma unroll
        for (int c = 0; c < N_CLS; ++c)
            wfr[r][c] = Wf[(lane * 8 + r) * N_CLS + c];
    float bfr[N_CLS];
    #pragma unroll
    for (int c = 0; c < N_CLS; ++c) bfr[c] = bf_[c];

    const int wid  = blockIdx.x * 4 + wv;
    const int step = gridDim.x * 4;
    for (int t = wid; t < Etr; t += step) {
        const int eid = tids[t];
        const size_t a = (size_t)ei[eid] * H_DIM + lane * 8;
        const size_t b = (size_t)ei[E + eid] * H_DIM + lane * 8;
        const ushort8 ah = *(const ushort8*)(hh + a);
        const ushort8 al = *(const ushort8*)(hl + a);
        const ushort8 bh = *(const ushort8*)(hh + b);
        const ushort8 bl = *(const ushort8*)(hl + b);
        float acc[N_CLS] = {0.f, 0.f, 0.f, 0.f, 0.f, 0.f, 0.f};
        #pragma unroll
        for (int r = 0; r < 8; ++r) {
            const float va = bf2f(ah[r]) + bf2f(al[r]);
            const float vb = bf2f(bh[r]) + bf2f(bl[r]);
            const float e = va * vb;
            #pragma unroll
            for (int c = 0; c < N_CLS; ++c) acc[c] = fmaf(e, wfr[r][c], acc[c]);
        }
        #pragma unroll
        for (int o = 32; o; o >>= 1)
            #pragma unroll
            for (int c = 0; c < N_CLS; ++c) acc[c] += __shfl_xor(acc[c], o, 64);
        if (lane == 0) {
            #pragma unroll
            for (int c = 0; c < N_CLS; ++c) out[(size_t)t * N_CLS + c] = acc[c] + bfr[c];
        }
    }
}

// ---------------- launch ----------------

extern "C" void kernel_launch(void* const* d_in, const int* in_sizes, int n_in,
                              void* d_out, int out_size, void* d_ws, size_t ws_size,
                              hipStream_t stream) {
    const float* x    = (const float*)d_in[0];
    const int*   ei   = (const int*)d_in[1];
    const int*   tids = (const int*)d_in[2];
    const float* eps1 = (const float*)d_in[3];
    const float* W1a  = (const float*)d_in[4];
    const float* b1a  = (const float*)d_in[5];
    const float* W1b  = (const float*)d_in[6];
    const float* b1b  = (const float*)d_in[7];
    const float* g1p  = (const float*)d_in[8];
    const float* be1  = (const float*)d_in[9];
    const float* rm1  = (const float*)d_in[10];
    const float* rv1  = (const float*)d_in[11];
    const float* eps2 = (const float*)d_in[12];
    const float* W2a  = (const float*)d_in[13];
    const float* b2a  = (const float*)d_in[14];
    const float* g2p  = (const float*)d_in[15];
    const float* be2  = (const float*)d_in[16];
    const float* rm2  = (const float*)d_in[17];
    const float* rv2  = (const float*)d_in[18];
    const float* Wl   = (const float*)d_in[19];
    const float* bl   = (const float*)d_in[20];
    const float* Wf   = (const float*)d_in[21];
    const float* bf   = (const float*)d_in[22];
    float* out = (float*)d_out;

    const int E   = in_sizes[1] / 2;
    const int Etr = in_sizes[2];

    char* ws = (char*)d_ws;
    size_t off = 0;
    auto alloc = [&](size_t bytes) -> char* {
        char* p = ws + off;
        off += (bytes + 255) & ~(size_t)255;
        return p;
    };
    int*    counts  = (int*)alloc((size_t)N_NODES * 4);
    int*    offsets = (int*)alloc((size_t)(N_NODES + 1) * 4);
    int*    cursor  = (int*)alloc((size_t)N_NODES * 4);
    int*    csr_src = (int*)alloc((size_t)E * 4);
    ushort* h0h = (ushort*)alloc((size_t)M_PAD * F_IN * 2);
    ushort* h0l = (ushort*)alloc((size_t)M_PAD * F_IN * 2);
    ushort* Ahh = (ushort*)alloc((size_t)M_PAD * H_DIM * 2);  // pair A
    ushort* Ahl = (ushort*)alloc((size_t)M_PAD * H_DIM * 2);
    ushort* Bhh = (ushort*)alloc((size_t)M_PAD * H_DIM * 2);  // pair B
    ushort* Bhl = (ushort*)alloc((size_t)M_PAD * H_DIM * 2);
    ushort* wt1a_h = (ushort*)alloc((size_t)H_DIM * F_IN * 2);
    ushort* wt1a_l = (ushort*)alloc((size_t)H_DIM * F_IN * 2);
    ushort* wt1b_h = (ushort*)alloc((size_t)H_DIM * H_DIM * 2);
    ushort* wt1b_l = (ushort*)alloc((size_t)H_DIM * H_DIM * 2);
    ushort* wt2a_h = (ushort*)alloc((size_t)H_DIM * H_DIM * 2);
    ushort* wt2a_l = (ushort*)alloc((size_t)H_DIM * H_DIM * 2);
    ushort* wtl_h  = (ushort*)alloc((size_t)H_DIM * H_DIM * 2);
    ushort* wtl_l  = (ushort*)alloc((size_t)H_DIM * H_DIM * 2);
    (void)ws_size; (void)n_in; (void)out_size;

    // CSR by dst
    k_zero_i32<<<(N_NODES + 255) / 256, 256, 0, stream>>>(counts, N_NODES);
    k_hist<<<(E + 255) / 256, 256, 0, stream>>>(ei, counts, E);
    k_scan<<<1, 1024, 0, stream>>>(counts, offsets, cursor, N_NODES, E);
    k_scatter<<<(E + 255) / 256, 256, 0, stream>>>(ei, cursor, csr_src, E);

    // all 4 weight splits in one launch
    k_wsplit_all<<<dim3(H_DIM / 32, H_DIM / 32, 4), 256, 0, stream>>>(
        W1a, wt1a_h, wt1a_l, W1b, wt1b_h, wt1b_l,
        W2a, wt2a_h, wt2a_l, Wl,  wtl_h,  wtl_l);

    // h0 = (1+eps1)*x + agg(x)  -> pair (2 nodes/wave, float4 gathers)
    k_agg_f32<<<(N_NODES + 7) / 8, 256, 0, stream>>>(x, csr_src, offsets, eps1, h0h, h0l);

    dim3 gdim(M_PAD / 64, H_DIM / 128);   // 158 x 4 = 632 blocks
    // h1 = relu(h0 @ W1a + b1a)            -> pair A
    k_gemm_mfma<0><<<gdim, 256, 0, stream>>>(h0h, h0l, wt1a_h, wt1a_l, b1a,
                                             nullptr, nullptr, nullptr, nullptr,
                                             Ahh, Ahl, F_IN, H_DIM);
    // h2 = bn1(relu(h1 @ W1b + b1b))       -> pair B
    k_gemm_mfma<1><<<gdim, 256, 0, stream>>>(Ahh, Ahl, wt1b_h, wt1b_l, b1b,
                                             g1p, be1, rm1, rv1,
                                             Bhh, Bhl, H_DIM, H_DIM);
    // h3 = (1+eps2)*h2 + agg(h2)           -> pair A (XCD column-chunked)
    k_agg_pair<<<(N_NODES / 16) * NCHUNK, 256, 0, stream>>>(Bhh, Bhl, csr_src, offsets, eps2, Ahh, Ahl);
    // h4 = bn2(relu(h3 @ W2a + b2a))       -> pair B
    k_gemm_mfma<1><<<gdim, 256, 0, stream>>>(Ahh, Ahl, wt2a_h, wt2a_l, b2a,
                                             g2p, be2, rm2, rv2,
                                             Bhh, Bhl, H_DIM, H_DIM);
    // h5 = relu(h4 @ Wl + bl)              -> pair A
    k_gemm_mfma<0><<<gdim, 256, 0, stream>>>(Bhh, Bhl, wtl_h, wtl_l, bl,
                                             nullptr, nullptr, nullptr, nullptr,
                                             Ahh, Ahl, H_DIM, H_DIM);
    // edge head (grid-stride, wf-in-registers)
    k_edge<<<2048, 256, 0, stream>>>(Ahh, Ahl, ei, tids, Wf, bf, out, Etr, E);
}

// Round 15
// 276.631 us; speedup vs baseline: 1.1517x; 1.1517x over previous
//
#include <hip/hip_runtime.h>
#include <hip/hip_bf16.h>

#define N_NODES 10000
#define M_PAD   10112   // 158*64
#define F_IN    128
#define H_DIM   512
#define N_CLS   7
#define NCHUNK  8
#define CCOLS   (H_DIM / NCHUNK)   // 64

typedef __bf16  bf16x8  __attribute__((ext_vector_type(8)));
typedef float   f32x4   __attribute__((ext_vector_type(4)));
typedef ushort  ushort8 __attribute__((ext_vector_type(8)));

__device__ __forceinline__ ushort f2bf(float f) {
    union { float f; unsigned u; } x; x.f = f;
    unsigned r = x.u + 0x7fffu + ((x.u >> 16) & 1u);
    return (ushort)(r >> 16);
}
__device__ __forceinline__ float bf2f(ushort h) {
    union { unsigned u; float f; } x; x.u = ((unsigned)h) << 16;
    return x.f;
}

__device__ __forceinline__ void gload16(const void* g, void* l) {
    __builtin_amdgcn_global_load_lds(
        (const __attribute__((address_space(1))) void*)g,
        (__attribute__((address_space(3))) void*)l, 16, 0, 0);
}

// ---------------- CSR build ----------------

__global__ void k_zero_i32(int* __restrict__ p, int n) {
    int i = blockIdx.x * blockDim.x + threadIdx.x;
    if (i < n) p[i] = 0;
}

__global__ void k_hist(const int* __restrict__ ei, int* __restrict__ counts, int E) {
    int e = blockIdx.x * blockDim.x + threadIdx.x;
    if (e < E) atomicAdd(&counts[ei[E + e]], 1);  // dst
}

__global__ __launch_bounds__(1024) void k_scan(const int* __restrict__ counts,
                                               int* __restrict__ offsets,
                                               int* __restrict__ cursor,
                                               int N, int E) {
    __shared__ int sm[1024];
    int t = threadIdx.x;
    int base = t * 10;
    int loc[10];
    int s = 0;
    #pragma unroll
    for (int i = 0; i < 10; ++i) {
        int idx = base + i;
        int c = (idx < N) ? counts[idx] : 0;
        loc[i] = s;
        s += c;
    }
    sm[t] = s;
    __syncthreads();
    for (int off = 1; off < 1024; off <<= 1) {
        int v = (t >= off) ? sm[t - off] : 0;
        __syncthreads();
        sm[t] += v;
        __syncthreads();
    }
    int excl = sm[t] - s;
    #pragma unroll
    for (int i = 0; i < 10; ++i) {
        int idx = base + i;
        if (idx < N) {
            int o = excl + loc[i];
            offsets[idx] = o;
            cursor[idx] = o;
        }
    }
    if (t == 0) offsets[N] = E;
}

__global__ void k_scatter(const int* __restrict__ ei, int* __restrict__ cursor,
                          int* __restrict__ csr_src, int E) {
    int e = blockIdx.x * blockDim.x + threadIdx.x;
    if (e < E) {
        int d = ei[E + e];
        int pos = atomicAdd(&cursor[d], 1);
        csr_src[pos] = ei[e];
    }
}

// ---------------- weight split, all 4 matrices in ONE launch ----------------
// W (K x N fp32) -> Wt_hi/Wt_lo (N x K bf16). Weights KEEP the hi/lo split
// (their quantization error is systematic across all rows). LDS 32x33 tile
// transpose, coalesced both sides.

__global__ __launch_bounds__(256) void k_wsplit_all(
    const float* __restrict__ W0, ushort* __restrict__ T0h, ushort* __restrict__ T0l,
    const float* __restrict__ W1, ushort* __restrict__ T1h, ushort* __restrict__ T1l,
    const float* __restrict__ W2, ushort* __restrict__ T2h, ushort* __restrict__ T2l,
    const float* __restrict__ W3, ushort* __restrict__ T3h, ushort* __restrict__ T3l) {
    const int z = blockIdx.z;
    const int K = (z == 0) ? F_IN : H_DIM;
    const int N = H_DIM;
    if (blockIdx.x * 32 >= K) return;
    const float* W;
    ushort *Th, *Tl;
    if (z == 0)      { W = W0; Th = T0h; Tl = T0l; }
    else if (z == 1) { W = W1; Th = T1h; Tl = T1l; }
    else if (z == 2) { W = W2; Th = T2h; Tl = T2l; }
    else             { W = W3; Th = T3h; Tl = T3l; }

    __shared__ float tile[32][33];
    const int bk = blockIdx.x * 32;
    const int bn = blockIdx.y * 32;
    const int c  = threadIdx.x & 31;
    const int r0 = threadIdx.x >> 5;   // 0..7
    #pragma unroll
    for (int i = 0; i < 4; ++i) {
        const int r = r0 + i * 8;
        tile[r][c] = W[(size_t)(bk + r) * N + bn + c];
    }
    __syncthreads();
    #pragma unroll
    for (int i = 0; i < 4; ++i) {
        const int r = r0 + i * 8;          // n-offset
        const float w = tile[c][r];        // = W[bk+c][bn+r]
        const ushort hb = f2bf(w);
        const size_t o = (size_t)(bn + r) * K + bk + c;   // consecutive c -> coalesced
        Th[o] = hb;
        Tl[o] = f2bf(w - bf2f(hb));
    }
}

// ---------------- GIN agg, fp32 input (F=128) -> bf16: 2 nodes/wave, float4/lane ---

__global__ __launch_bounds__(256) void k_agg_f32(
    const float* __restrict__ X, const int* __restrict__ csr,
    const int* __restrict__ offs, const float* __restrict__ eps,
    ushort* __restrict__ Oh) {
    const int wv = threadIdx.x >> 6, lane = threadIdx.x & 63;
    const int half = lane >> 5, sub = lane & 31;
    const int n = blockIdx.x * 8 + wv * 2 + half;
    if (n >= N_NODES) return;
    const int c0 = sub * 4;
    const int s0 = offs[n], s1 = offs[n + 1];
    float4 a = {0.f, 0.f, 0.f, 0.f};
    for (int i = s0; i < s1; ++i) {
        const float4 v = *(const float4*)(X + (size_t)csr[i] * F_IN + c0);
        a.x += v.x; a.y += v.y; a.z += v.z; a.w += v.w;
    }
    const float4 sv = *(const float4*)(X + (size_t)n * F_IN + c0);
    const float e = 1.f + eps[0];
    ushort4 oh;
    oh.x = f2bf(e * sv.x + a.x);
    oh.y = f2bf(e * sv.y + a.y);
    oh.z = f2bf(e * sv.z + a.z);
    oh.w = f2bf(e * sv.w + a.w);
    *(ushort4*)(Oh + (size_t)n * F_IN + c0) = oh;
}

// ---------------- GIN agg, bf16 input (F=512): XCD column-chunked ----------------
// Single plane now: 8 thr/node x ushort8 = 64 cols = one chunk; 32 nodes per
// 256-thr block; chunk = blockIdx&7 pins each 1.28 MB column slab to one
// XCD's L2 (round-robin dispatch). Gather count halved vs pair version.

__global__ __launch_bounds__(256) void k_agg_bf16(
    const ushort* __restrict__ Xh, const int* __restrict__ csr,
    const int* __restrict__ offs, const float* __restrict__ eps,
    ushort* __restrict__ Oh) {
    const int chunk = blockIdx.x & (NCHUNK - 1);
    const int grp   = blockIdx.x >> 3;
    const int n     = grp * 32 + (threadIdx.x >> 3);
    if (n >= N_NODES) return;
    const int col   = chunk * CCOLS + (threadIdx.x & 7) * 8;

    const int s0 = offs[n], s1 = offs[n + 1];
    float acc[8] = {0.f, 0.f, 0.f, 0.f, 0.f, 0.f, 0.f, 0.f};
    for (int i = s0; i < s1; ++i) {
        const ushort8 v = *(const ushort8*)(Xh + (size_t)csr[i] * H_DIM + col);
        #pragma unroll
        for (int r = 0; r < 8; ++r) acc[r] += bf2f(v[r]);
    }
    const ushort8 sv = *(const ushort8*)(Xh + (size_t)n * H_DIM + col);
    const float e = 1.f + eps[0];
    ushort8 oh;
    #pragma unroll
    for (int r = 0; r < 8; ++r) oh[r] = f2bf(e * bf2f(sv[r]) + acc[r]);
    *(ushort8*)(Oh + (size_t)n * H_DIM + col) = oh;
}

// ---------------- bf16-A x split-W MFMA GEMM ----------------
// C = ep(A @ W + bias); A plain bf16 (M x K), W hi/lo pair transposed [N][K].
// 64x128 tile, BK=32, 4 waves 2x2 (32x64 each), mfma_f32_16x16x32_bf16,
// 2 MFMA terms (a*w_hi + a*w_lo) — W split is exact, A carries one bf16
// rounding per layer (error budget ~0.2% rel/layer, under threshold).
// LDS 20KB -> high occupancy; single-buffered (dbuf measured neutral, r12/13).

template <int DO_BN>
__global__ __launch_bounds__(256) void k_gemm_mfma(
    const ushort* __restrict__ Ax,
    const ushort* __restrict__ Wh, const ushort* __restrict__ Wlo,
    const float* __restrict__ bias,
    const float* __restrict__ g, const float* __restrict__ be,
    const float* __restrict__ rm, const float* __restrict__ rv,
    ushort* __restrict__ Oh,
    int K, int Nout) {
    __shared__ __align__(16) ushort As[64][32];
    __shared__ __align__(16) ushort Bs_h[128][32];
    __shared__ __align__(16) ushort Bs_l[128][32];

    const int tid  = threadIdx.x;
    const int lane = tid & 63;
    const int wid  = tid >> 6;
    const int wm   = wid >> 1, wn = wid & 1;   // 2x2 waves, wave tile 32x64
    const int bm = blockIdx.x * 64, bn = blockIdx.y * 128;
    const int rsel = lane & 15;
    const int kh   = (lane >> 4) * 8;

    f32x4 acc[2][4];
    #pragma unroll
    for (int m = 0; m < 2; ++m)
        #pragma unroll
        for (int n = 0; n < 4; ++n) {
            acc[m][n][0] = 0.f; acc[m][n][1] = 0.f;
            acc[m][n][2] = 0.f; acc[m][n][3] = 0.f;
        }

    for (int k0 = 0; k0 < K; k0 += 32) {
        {
            const int off = tid * 16;          // A: 64x32 = 4KB, one gload16/thread
            const int row = off >> 6;
            const int ke  = (off & 63) >> 1;
            gload16(Ax + (size_t)(bm + row) * K + (k0 + ke), (char*)As + off);
        }
        #pragma unroll
        for (int c = 0; c < 2; ++c) {
            const int off = tid * 16 + c * 4096;  // B: 128x32 = 8KB/plane
            const int row = off >> 6;
            const int ke  = (off & 63) >> 1;
            const size_t gb = (size_t)(bn + row) * K + (k0 + ke);
            gload16(Wh + gb,  (char*)Bs_h + off);
            gload16(Wlo + gb, (char*)Bs_l + off);
        }
        __syncthreads();
        bf16x8 a[2], b_h[4], b_l[4];
        #pragma unroll
        for (int m = 0; m < 2; ++m)
            a[m] = *(const bf16x8*)&As[wm * 32 + m * 16 + rsel][kh];
        #pragma unroll
        for (int n = 0; n < 4; ++n) {
            const int r = wn * 64 + n * 16 + rsel;
            b_h[n] = *(const bf16x8*)&Bs_h[r][kh];
            b_l[n] = *(const bf16x8*)&Bs_l[r][kh];
        }
        #pragma unroll
        for (int m = 0; m < 2; ++m)
            #pragma unroll
            for (int n = 0; n < 4; ++n) {
                acc[m][n] = __builtin_amdgcn_mfma_f32_16x16x32_bf16(a[m], b_h[n], acc[m][n], 0, 0, 0);
                acc[m][n] = __builtin_amdgcn_mfma_f32_16x16x32_bf16(a[m], b_l[n], acc[m][n], 0, 0, 0);
            }
        __syncthreads();
    }

    float bs[4], sc[4], sh[4];
    int cols[4];
    #pragma unroll
    for (int n = 0; n < 4; ++n) {
        const int col = bn + wn * 64 + n * 16 + rsel;
        cols[n] = col;
        bs[n] = bias[col];
        if (DO_BN) {
            const float s = g[col] * rsqrtf(rv[col] + 1e-5f);
            sc[n] = s;
            sh[n] = be[col] - rm[col] * s;
        } else {
            sc[n] = 0.f; sh[n] = 0.f;
        }
    }
    #pragma unroll
    for (int m = 0; m < 2; ++m) {
        #pragma unroll
        for (int r = 0; r < 4; ++r) {
            const int row = bm + wm * 32 + m * 16 + (lane >> 4) * 4 + r;
            #pragma unroll
            for (int n = 0; n < 4; ++n) {
                float v = acc[m][n][r] + bs[n];
                v = fmaxf(v, 0.f);
                if (DO_BN) v = v * sc[n] + sh[n];
                Oh[(size_t)row * Nout + cols[n]] = f2bf(v);
            }
        }
    }
}

// ---------------- edge head: out[t] = (h[a]*h[b]) @ Wf + bf ----------------
// Single-plane h: 2 gathers per edge side (was 4).

__global__ __launch_bounds__(256) void k_edge(
    const ushort* __restrict__ hh,
    const int* __restrict__ ei, const int* __restrict__ tids,
    const float* __restrict__ Wf, const float* __restrict__ bf_,
    float* __restrict__ out, int Etr, int E) {
    const int lane = threadIdx.x & 63;
    const int wv   = threadIdx.x >> 6;
    float wfr[8][N_CLS];
    #pragma unroll
    for (int r = 0; r < 8; ++r)
        #pragma unroll
        for (int c = 0; c < N_CLS; ++c)
            wfr[r][c] = Wf[(lane * 8 + r) * N_CLS + c];
    float bfr[N_CLS];
    #pragma unroll
    for (int c = 0; c < N_CLS; ++c) bfr[c] = bf_[c];

    const int wid  = blockIdx.x * 4 + wv;
    const int step = gridDim.x * 4;
    for (int t = wid; t < Etr; t += step) {
        const int eid = tids[t];
        const size_t a = (size_t)ei[eid] * H_DIM + lane * 8;
        const size_t b = (size_t)ei[E + eid] * H_DIM + lane * 8;
        const ushort8 ah = *(const ushort8*)(hh + a);
        const ushort8 bh = *(const ushort8*)(hh + b);
        float acc[N_CLS] = {0.f, 0.f, 0.f, 0.f, 0.f, 0.f, 0.f};
        #pragma unroll
        for (int r = 0; r < 8; ++r) {
            const float e = bf2f(ah[r]) * bf2f(bh[r]);
            #pragma unroll
            for (int c = 0; c < N_CLS; ++c) acc[c] = fmaf(e, wfr[r][c], acc[c]);
        }
        #pragma unroll
        for (int o = 32; o; o >>= 1)
            #pragma unroll
            for (int c = 0; c < N_CLS; ++c) acc[c] += __shfl_xor(acc[c], o, 64);
        if (lane == 0) {
            #pragma unroll
            for (int c = 0; c < N_CLS; ++c) out[(size_t)t * N_CLS + c] = acc[c] + bfr[c];
        }
    }
}

// ---------------- launch ----------------

extern "C" void kernel_launch(void* const* d_in, const int* in_sizes, int n_in,
                              void* d_out, int out_size, void* d_ws, size_t ws_size,
                              hipStream_t stream) {
    const float* x    = (const float*)d_in[0];
    const int*   ei   = (const int*)d_in[1];
    const int*   tids = (const int*)d_in[2];
    const float* eps1 = (const float*)d_in[3];
    const float* W1a  = (const float*)d_in[4];
    const float* b1a  = (const float*)d_in[5];
    const float* W1b  = (const float*)d_in[6];
    const float* b1b  = (const float*)d_in[7];
    const float* g1p  = (const float*)d_in[8];
    const float* be1  = (const float*)d_in[9];
    const float* rm1  = (const float*)d_in[10];
    const float* rv1  = (const float*)d_in[11];
    const float* eps2 = (const float*)d_in[12];
    const float* W2a  = (const float*)d_in[13];
    const float* b2a  = (const float*)d_in[14];
    const float* g2p  = (const float*)d_in[15];
    const float* be2  = (const float*)d_in[16];
    const float* rm2  = (const float*)d_in[17];
    const float* rv2  = (const float*)d_in[18];
    const float* Wl   = (const float*)d_in[19];
    const float* bl   = (const float*)d_in[20];
    const float* Wf   = (const float*)d_in[21];
    const float* bf   = (const float*)d_in[22];
    float* out = (float*)d_out;

    const int E   = in_sizes[1] / 2;
    const int Etr = in_sizes[2];

    char* ws = (char*)d_ws;
    size_t off = 0;
    auto alloc = [&](size_t bytes) -> char* {
        char* p = ws + off;
        off += (bytes + 255) & ~(size_t)255;
        return p;
    };
    int*    counts  = (int*)alloc((size_t)N_NODES * 4);
    int*    offsets = (int*)alloc((size_t)(N_NODES + 1) * 4);
    int*    cursor  = (int*)alloc((size_t)N_NODES * 4);
    int*    csr_src = (int*)alloc((size_t)E * 4);
    ushort* h0h = (ushort*)alloc((size_t)M_PAD * F_IN * 2);
    ushort* Ah  = (ushort*)alloc((size_t)M_PAD * H_DIM * 2);  // activation buf A
    ushort* Bh  = (ushort*)alloc((size_t)M_PAD * H_DIM * 2);  // activation buf B
    ushort* wt1a_h = (ushort*)alloc((size_t)H_DIM * F_IN * 2);
    ushort* wt1a_l = (ushort*)alloc((size_t)H_DIM * F_IN * 2);
    ushort* wt1b_h = (ushort*)alloc((size_t)H_DIM * H_DIM * 2);
    ushort* wt1b_l = (ushort*)alloc((size_t)H_DIM * H_DIM * 2);
    ushort* wt2a_h = (ushort*)alloc((size_t)H_DIM * H_DIM * 2);
    ushort* wt2a_l = (ushort*)alloc((size_t)H_DIM * H_DIM * 2);
    ushort* wtl_h  = (ushort*)alloc((size_t)H_DIM * H_DIM * 2);
    ushort* wtl_l  = (ushort*)alloc((size_t)H_DIM * H_DIM * 2);
    (void)ws_size; (void)n_in; (void)out_size;

    // CSR by dst
    k_zero_i32<<<(N_NODES + 255) / 256, 256, 0, stream>>>(counts, N_NODES);
    k_hist<<<(E + 255) / 256, 256, 0, stream>>>(ei, counts, E);
    k_scan<<<1, 1024, 0, stream>>>(counts, offsets, cursor, N_NODES, E);
    k_scatter<<<(E + 255) / 256, 256, 0, stream>>>(ei, cursor, csr_src, E);

    // all 4 weight splits in one launch
    k_wsplit_all<<<dim3(H_DIM / 32, H_DIM / 32, 4), 256, 0, stream>>>(
        W1a, wt1a_h, wt1a_l, W1b, wt1b_h, wt1b_l,
        W2a, wt2a_h, wt2a_l, Wl,  wtl_h,  wtl_l);

    // h0 = (1+eps1)*x + agg(x)  -> bf16
    k_agg_f32<<<(N_NODES + 7) / 8, 256, 0, stream>>>(x, csr_src, offsets, eps1, h0h);

    dim3 gdim(M_PAD / 64, H_DIM / 128);   // 158 x 4 = 632 blocks
    // h1 = relu(h0 @ W1a + b1a)            -> Ah
    k_gemm_mfma<0><<<gdim, 256, 0, stream>>>(h0h, wt1a_h, wt1a_l, b1a,
                                             nullptr, nullptr, nullptr, nullptr,
                                             Ah, F_IN, H_DIM);
    // h2 = bn1(relu(h1 @ W1b + b1b))       -> Bh
    k_gemm_mfma<1><<<gdim, 256, 0, stream>>>(Ah, wt1b_h, wt1b_l, b1b,
                                             g1p, be1, rm1, rv1,
                                             Bh, H_DIM, H_DIM);
    // h3 = (1+eps2)*h2 + agg(h2)           -> Ah (XCD column-chunked)
    k_agg_bf16<<<((N_NODES + 31) / 32) * NCHUNK, 256, 0, stream>>>(
        Bh, csr_src, offsets, eps2, Ah);
    // h4 = bn2(relu(h3 @ W2a + b2a))       -> Bh
    k_gemm_mfma<1><<<gdim, 256, 0, stream>>>(Ah, wt2a_h, wt2a_l, b2a,
                                             g2p, be2, rm2, rv2,
                                             Bh, H_DIM, H_DIM);
    // h5 = relu(h4 @ Wl + bl)              -> Ah
    k_gemm_mfma<0><<<gdim, 256, 0, stream>>>(Bh, wtl_h, wtl_l, bl,
                                             nullptr, nullptr, nullptr, nullptr,
                                             Ah, H_DIM, H_DIM);
    // edge head (grid-stride, wf-in-registers, single-plane h)
    k_edge<<<2048, 256, 0, stream>>>(Ah, ei, tids, Wf, bf, out, Etr, E);
}